// Round 1
// baseline (481.347 us; speedup 1.0000x reference)
//
#include <hip/hip_runtime.h>
#include <hip/hip_bf16.h>

#define BATCH   4096
#define DIM     64
#define HID     256
#define TSTEPS  200
#define SROWS   16                 // samples per block
#define NBLOCKS (BATCH / SROWS)    // 256
#define NTHREADS 256

#define HP 264   // padded LDS stride for h1/h2 (256 + 8 bf16)
#define YP 72    // padded LDS stride for ybf  (64 + 8 bf16)

typedef __bf16 bf16_t;
typedef bf16_t bf16x8 __attribute__((ext_vector_type(8)));
typedef float  f32x4  __attribute__((ext_vector_type(4)));

__device__ __forceinline__ unsigned short f2bf(float f) {
    unsigned u = __builtin_bit_cast(unsigned, f);
    u += 0x7FFFu + ((u >> 16) & 1u);   // RNE
    return (unsigned short)(u >> 16);
}

// ---------------------------------------------------------------------------
// Weight prep: fp32 row-major W[K][N] -> bf16 MFMA-B-fragment order in ws.
// Unit u = one lane's 8 bf16 (16B). Layouts:
//   W1: u = ((w*2+kk)*4+nt)*64+lane            (units [0,2048))
//   W2: u = 2048 + ((w*8+kk)*4+nt)*64+lane     (units [2048,10240))
//   W3: u = 10240 + (w*8+kk)*64+lane           (units [10240,12288))
// B-frag element j:  k = kk*32 + (lane>>4)*8 + j,  n = colbase + (lane&15)
// ---------------------------------------------------------------------------
__global__ void prep_weights(const float* __restrict__ W1,
                             const float* __restrict__ W2,
                             const float* __restrict__ W3,
                             unsigned short* __restrict__ ws) {
    int u = blockIdx.x * blockDim.x + threadIdx.x;
    if (u >= 12288) return;
    const float* src; int k, n, ldn;
    if (u < 2048) {
        int r = u; int lane = r & 63; r >>= 6;
        int nt = r & 3; r >>= 2; int kk = r & 1; r >>= 1; int w = r;
        n = w * 64 + nt * 16 + (lane & 15);
        k = kk * 32 + (lane >> 4) * 8;
        src = W1; ldn = 256;
    } else if (u < 10240) {
        int r = u - 2048; int lane = r & 63; r >>= 6;
        int nt = r & 3; r >>= 2; int kk = r & 7; r >>= 3; int w = r;
        n = w * 64 + nt * 16 + (lane & 15);
        k = kk * 32 + (lane >> 4) * 8;
        src = W2; ldn = 256;
    } else {
        int r = u - 10240; int lane = r & 63; r >>= 6;
        int kk = r & 7; r >>= 3; int w = r;
        n = w * 16 + (lane & 15);
        k = kk * 32 + (lane >> 4) * 8;
        src = W3; ldn = 64;
    }
    unsigned short tmp[8] __attribute__((aligned(16)));
    #pragma unroll
    for (int j = 0; j < 8; ++j)
        tmp[j] = f2bf(src[(size_t)(k + j) * ldn + n]);
    *(uint4*)(ws + (size_t)u * 8) = *(const uint4*)tmp;
}

// ---------------------------------------------------------------------------
// Persistent ODE kernel: each block owns SROWS samples for all 199 steps.
// Wave w owns output cols [64w,64w+64) of h1/h2 and [16w,16w+16) of dy.
// W1/W2/W3 fragments live in registers (loaded once). h1/h2/y in LDS.
// ---------------------------------------------------------------------------
__global__ void __launch_bounds__(NTHREADS, 1)
ode_kernel(const float* __restrict__ y0,
           const float* __restrict__ tarr,
           const float* __restrict__ b1,
           const float* __restrict__ b2,
           const float* __restrict__ b3,
           const unsigned short* __restrict__ wf,
           float* __restrict__ out) {
    __shared__ __align__(16) float          y32[SROWS * DIM];
    __shared__ __align__(16) unsigned short ybf[SROWS * YP];
    __shared__ __align__(16) unsigned short h1s[SROWS * HP];
    __shared__ __align__(16) unsigned short h2s[SROWS * HP];

    const int tid  = threadIdx.x;
    const int w    = tid >> 6;
    const int lane = tid & 63;
    const int l16  = lane & 15;
    const int quad = lane >> 4;
    const int b0   = blockIdx.x * SROWS;

    const float dt = tarr[1] - tarr[0];

    // --- load resident weight fragments (one-time) ---
    const bf16x8* wv = (const bf16x8*)wf;
    bf16x8 w1f[2][4], w2f[8][4], w3f[8];
    #pragma unroll
    for (int kk = 0; kk < 2; ++kk)
        #pragma unroll
        for (int nt = 0; nt < 4; ++nt)
            w1f[kk][nt] = wv[((w * 2 + kk) * 4 + nt) * 64 + lane];
    #pragma unroll
    for (int kk = 0; kk < 8; ++kk)
        #pragma unroll
        for (int nt = 0; nt < 4; ++nt)
            w2f[kk][nt] = wv[2048 + ((w * 8 + kk) * 4 + nt) * 64 + lane];
    #pragma unroll
    for (int kk = 0; kk < 8; ++kk)
        w3f[kk] = wv[10240 + (w * 8 + kk) * 64 + lane];

    // --- biases for this lane's output columns ---
    float b1r[4], b2r[4];
    #pragma unroll
    for (int nt = 0; nt < 4; ++nt) {
        b1r[nt] = b1[w * 64 + nt * 16 + l16];
        b2r[nt] = b2[w * 64 + nt * 16 + l16];
    }
    const float b3r = b3[w * 16 + l16];

    // --- init y state + write t=0 slice ---
    {
        const int r  = tid >> 4;         // 0..15
        const int c4 = (tid & 15) * 4;   // 0..60
        float4 v = *(const float4*)&y0[(size_t)(b0 + r) * DIM + c4];
        y32[r * DIM + c4 + 0] = v.x;  y32[r * DIM + c4 + 1] = v.y;
        y32[r * DIM + c4 + 2] = v.z;  y32[r * DIM + c4 + 3] = v.w;
        ybf[r * YP + c4 + 0] = f2bf(v.x);  ybf[r * YP + c4 + 1] = f2bf(v.y);
        ybf[r * YP + c4 + 2] = f2bf(v.z);  ybf[r * YP + c4 + 3] = f2bf(v.w);
        *(float4*)&out[(size_t)(b0 + r) * (TSTEPS * DIM) + c4] = v;
    }
    __syncthreads();

    const f32x4 zero4 = {0.f, 0.f, 0.f, 0.f};

    for (int t = 1; t < TSTEPS; ++t) {
        // ---------------- GEMM1: h1 = relu(y @ W1 + b1) ----------------
        f32x4 acc1[4] = {zero4, zero4, zero4, zero4};
        #pragma unroll
        for (int kk = 0; kk < 2; ++kk) {
            bf16x8 a = *(const bf16x8*)&ybf[l16 * YP + kk * 32 + quad * 8];
            #pragma unroll
            for (int nt = 0; nt < 4; ++nt)
                acc1[nt] = __builtin_amdgcn_mfma_f32_16x16x32_bf16(
                    a, w1f[kk][nt], acc1[nt], 0, 0, 0);
        }
        #pragma unroll
        for (int nt = 0; nt < 4; ++nt)
            #pragma unroll
            for (int r = 0; r < 4; ++r) {
                float v = acc1[nt][r] + b1r[nt];
                v = v > 0.f ? v : 0.f;
                h1s[(quad * 4 + r) * HP + w * 64 + nt * 16 + l16] = f2bf(v);
            }
        __syncthreads();

        // ---------------- GEMM2: h2 = relu(h1 @ W2 + b2) ----------------
        f32x4 acc2[4] = {zero4, zero4, zero4, zero4};
        #pragma unroll
        for (int kk = 0; kk < 8; ++kk) {
            bf16x8 a = *(const bf16x8*)&h1s[l16 * HP + kk * 32 + quad * 8];
            #pragma unroll
            for (int nt = 0; nt < 4; ++nt)
                acc2[nt] = __builtin_amdgcn_mfma_f32_16x16x32_bf16(
                    a, w2f[kk][nt], acc2[nt], 0, 0, 0);
        }
        #pragma unroll
        for (int nt = 0; nt < 4; ++nt)
            #pragma unroll
            for (int r = 0; r < 4; ++r) {
                float v = acc2[nt][r] + b2r[nt];
                v = v > 0.f ? v : 0.f;
                h2s[(quad * 4 + r) * HP + w * 64 + nt * 16 + l16] = f2bf(v);
            }
        __syncthreads();

        // ---------------- GEMM3: dy = h2 @ W3 + b3; y += dt*dy ----------------
        f32x4 acc3 = zero4;
        #pragma unroll
        for (int kk = 0; kk < 8; ++kk) {
            bf16x8 a = *(const bf16x8*)&h2s[l16 * HP + kk * 32 + quad * 8];
            acc3 = __builtin_amdgcn_mfma_f32_16x16x32_bf16(
                a, w3f[kk], acc3, 0, 0, 0);
        }
        const int col = w * 16 + l16;
        #pragma unroll
        for (int r = 0; r < 4; ++r) {
            const int row = quad * 4 + r;
            float yn = y32[row * DIM + col] + dt * (acc3[r] + b3r);
            y32[row * DIM + col] = yn;
            ybf[row * YP + col]  = f2bf(yn);
            out[(size_t)(b0 + row) * (TSTEPS * DIM) + (size_t)t * DIM + col] = yn;
        }
        __syncthreads();
    }
}

extern "C" void kernel_launch(void* const* d_in, const int* in_sizes, int n_in,
                              void* d_out, int out_size, void* d_ws, size_t ws_size,
                              hipStream_t stream) {
    const float* y0 = (const float*)d_in[0];
    const float* t  = (const float*)d_in[1];
    const float* W1 = (const float*)d_in[2];
    const float* b1 = (const float*)d_in[3];
    const float* W2 = (const float*)d_in[4];
    const float* b2 = (const float*)d_in[5];
    const float* W3 = (const float*)d_in[6];
    const float* b3 = (const float*)d_in[7];
    float* out = (float*)d_out;
    unsigned short* wf = (unsigned short*)d_ws;   // 12288 * 16B = 192 KiB

    prep_weights<<<48, 256, 0, stream>>>(W1, W2, W3, wf);
    ode_kernel<<<NBLOCKS, NTHREADS, 0, stream>>>(y0, t, b1, b2, b3, wf, out);
}

// Round 2
// 395.308 us; speedup vs baseline: 1.2177x; 1.2177x over previous
//
#include <hip/hip_runtime.h>
#include <hip/hip_bf16.h>

#define BATCH   4096
#define DIM     64
#define HID     256
#define TSTEPS  200
#define SROWS   16                 // samples per block (MFMA N)
#define NBLOCKS (BATCH / SROWS)    // 256 blocks = 1 per CU
#define NTH     512                // 8 waves, 2 per SIMD

#define HP  264   // shorts: h1s/h2s row stride ([sample][h]), 256+8 -> 2-way banks (free)
#define YPB 72    // shorts: ybt row stride ([sample][d]), 64+8

typedef __bf16 bf16_t;
typedef bf16_t bf16x8 __attribute__((ext_vector_type(8)));
typedef float  f32x4  __attribute__((ext_vector_type(4)));

__device__ __forceinline__ unsigned short f2bf(float f) {
    unsigned u = __builtin_bit_cast(unsigned, f);
    u += 0x7FFFu + ((u >> 16) & 1u);   // RNE
    return (unsigned short)(u >> 16);
}
__device__ __forceinline__ unsigned pk2(float lo, float hi) {
    return (unsigned)f2bf(lo) | ((unsigned)f2bf(hi) << 16);
}

// ---------------------------------------------------------------------------
// Weight prep: fp32 row-major W[K][M] -> bf16 MFMA **A-fragment** order of W^T.
// A-frag for 16xK tile: lane(quad,l16) element j = W^T[mt*16+l16][kk*32+quad*8+j]
//                                               = W[(kk*32+quad*8+j)][mt*16+l16]
// Unit u (8 bf16 = 16B):
//   W1^T: u = (mt*2+kk)*64+lane            mt:0..15 (H=256), kk:0..1 (K=D=64)
//   W2^T: u = 2048 + (mt*8+kk)*64+lane     mt:0..15, kk:0..7 (K=H=256)
//   W3^T: u = 10240 + (mt*8+kk)*64+lane    mt:0..3 (D=64),  kk:0..7 (K=H=256)
// ---------------------------------------------------------------------------
__global__ void prep_weights(const float* __restrict__ W1,
                             const float* __restrict__ W2,
                             const float* __restrict__ W3,
                             unsigned short* __restrict__ ws) {
    int u = blockIdx.x * blockDim.x + threadIdx.x;
    if (u >= 12288) return;
    const int lane = u & 63, l16 = lane & 15, quad = lane >> 4;
    const float* src; int ld, m, k;
    if (u < 2048) {
        int r = u >> 6; int kk = r & 1; int mt = r >> 1;
        src = W1; ld = 256; m = mt * 16 + l16; k = kk * 32 + quad * 8;
    } else if (u < 10240) {
        int r = (u - 2048) >> 6; int kk = r & 7; int mt = r >> 3;
        src = W2; ld = 256; m = mt * 16 + l16; k = kk * 32 + quad * 8;
    } else {
        int r = (u - 10240) >> 6; int kk = r & 7; int mt = r >> 3;
        src = W3; ld = 64;  m = mt * 16 + l16; k = kk * 32 + quad * 8;
    }
    unsigned short tmp[8] __attribute__((aligned(16)));
    #pragma unroll
    for (int j = 0; j < 8; ++j)
        tmp[j] = f2bf(src[(size_t)(k + j) * ld + m]);
    *(uint4*)(ws + (size_t)u * 8) = *(const uint4*)tmp;
}

// ---------------------------------------------------------------------------
// Persistent ODE kernel, transposed formulation: h^T[H x 16samples].
//   MFMA A = weight^T frags (registers, loaded once), B = activations^T (LDS),
//   C/D: row = h-idx (quad*4+r), col = sample (l16).
// 8 waves: wave w owns h-rows [32w, 32w+32). GEMM3 by waves 0-3 (dy tile w),
// fp32 y-state lives in worker registers; only bf16 y^T round-trips LDS.
// ---------------------------------------------------------------------------
__global__ void __launch_bounds__(NTH, 2)
ode_kernel(const float* __restrict__ y0,
           const float* __restrict__ tarr,
           const float* __restrict__ b1,
           const float* __restrict__ b2,
           const float* __restrict__ b3,
           const unsigned short* __restrict__ wf,
           float* __restrict__ out) {
    __shared__ __align__(16) unsigned short ybt[SROWS * YPB];
    __shared__ __align__(16) unsigned short h1s[SROWS * HP];
    __shared__ __align__(16) unsigned short h2s[SROWS * HP];

    const int tid  = threadIdx.x;
    const int w    = tid >> 6;        // wave 0..7
    const int lane = tid & 63;
    const int l16  = lane & 15;       // sample within tile
    const int quad = lane >> 4;
    const int b0   = blockIdx.x * SROWS;

    const float dt = tarr[1] - tarr[0];

    // --- resident weight fragments ---
    const bf16x8* wv = (const bf16x8*)wf;
    bf16x8 w1f[2][2], w2f[2][8], w3f[8];
    #pragma unroll
    for (int mt = 0; mt < 2; ++mt) {
        const int g = w * 2 + mt;     // global 16-row h-tile
        #pragma unroll
        for (int kk = 0; kk < 2; ++kk) w1f[mt][kk] = wv[(g * 2 + kk) * 64 + lane];
        #pragma unroll
        for (int kk = 0; kk < 8; ++kk) w2f[mt][kk] = wv[2048 + (g * 8 + kk) * 64 + lane];
    }
    if (w < 4)
        #pragma unroll
        for (int kk = 0; kk < 8; ++kk) w3f[kk] = wv[10240 + (w * 8 + kk) * 64 + lane];

    // --- biases (per-register: h-row = base + quad*4 + r) ---
    float b1r[2][4], b2r[2][4], b3r[4], yreg[4];
    #pragma unroll
    for (int mt = 0; mt < 2; ++mt)
        #pragma unroll
        for (int r = 0; r < 4; ++r) {
            b1r[mt][r] = b1[w * 32 + mt * 16 + quad * 4 + r];
            b2r[mt][r] = b2[w * 32 + mt * 16 + quad * 4 + r];
        }

    // --- init y-state (workers) + t=0 output + ybt ---
    if (w < 4) {
        #pragma unroll
        for (int r = 0; r < 4; ++r) b3r[r] = b3[w * 16 + quad * 4 + r];
        float4 v = *(const float4*)&y0[(size_t)(b0 + l16) * DIM + w * 16 + quad * 4];
        yreg[0] = v.x; yreg[1] = v.y; yreg[2] = v.z; yreg[3] = v.w;
        uint2 p; p.x = pk2(v.x, v.y); p.y = pk2(v.z, v.w);
        *(uint2*)&ybt[l16 * YPB + w * 16 + quad * 4] = p;
        *(float4*)&out[(size_t)(b0 + l16) * (TSTEPS * DIM) + w * 16 + quad * 4] = v;
    }
    __syncthreads();

    const f32x4 zero4 = {0.f, 0.f, 0.f, 0.f};

    for (int t = 1; t < TSTEPS; ++t) {
        // ---- GEMM1: h1^T = W1^T @ y^T, relu ----
        {
            f32x4 acc[2] = {zero4, zero4};
            bf16x8 bf[2];
            #pragma unroll
            for (int kk = 0; kk < 2; ++kk)
                bf[kk] = *(const bf16x8*)&ybt[l16 * YPB + kk * 32 + quad * 8];
            #pragma unroll
            for (int kk = 0; kk < 2; ++kk)
                #pragma unroll
                for (int mt = 0; mt < 2; ++mt)
                    acc[mt] = __builtin_amdgcn_mfma_f32_16x16x32_bf16(
                        w1f[mt][kk], bf[kk], acc[mt], 0, 0, 0);
            #pragma unroll
            for (int mt = 0; mt < 2; ++mt) {
                float v0 = acc[mt][0] + b1r[mt][0]; v0 = v0 > 0.f ? v0 : 0.f;
                float v1 = acc[mt][1] + b1r[mt][1]; v1 = v1 > 0.f ? v1 : 0.f;
                float v2 = acc[mt][2] + b1r[mt][2]; v2 = v2 > 0.f ? v2 : 0.f;
                float v3 = acc[mt][3] + b1r[mt][3]; v3 = v3 > 0.f ? v3 : 0.f;
                uint2 p; p.x = pk2(v0, v1); p.y = pk2(v2, v3);
                *(uint2*)&h1s[l16 * HP + w * 32 + mt * 16 + quad * 4] = p;
            }
        }
        __syncthreads();

        // ---- GEMM2: h2^T = W2^T @ h1^T, relu ----
        {
            f32x4 acc[2] = {zero4, zero4};
            bf16x8 bf[8];
            #pragma unroll
            for (int kk = 0; kk < 8; ++kk)
                bf[kk] = *(const bf16x8*)&h1s[l16 * HP + kk * 32 + quad * 8];
            #pragma unroll
            for (int kk = 0; kk < 8; ++kk)
                #pragma unroll
                for (int mt = 0; mt < 2; ++mt)
                    acc[mt] = __builtin_amdgcn_mfma_f32_16x16x32_bf16(
                        w2f[mt][kk], bf[kk], acc[mt], 0, 0, 0);
            #pragma unroll
            for (int mt = 0; mt < 2; ++mt) {
                float v0 = acc[mt][0] + b2r[mt][0]; v0 = v0 > 0.f ? v0 : 0.f;
                float v1 = acc[mt][1] + b2r[mt][1]; v1 = v1 > 0.f ? v1 : 0.f;
                float v2 = acc[mt][2] + b2r[mt][2]; v2 = v2 > 0.f ? v2 : 0.f;
                float v3 = acc[mt][3] + b2r[mt][3]; v3 = v3 > 0.f ? v3 : 0.f;
                uint2 p; p.x = pk2(v0, v1); p.y = pk2(v2, v3);
                *(uint2*)&h2s[l16 * HP + w * 32 + mt * 16 + quad * 4] = p;
            }
        }
        __syncthreads();

        // ---- GEMM3 (waves 0-3): dy^T tile w = W3^T @ h2^T; y += dt*dy ----
        if (w < 4) {
            f32x4 acc = zero4;
            bf16x8 bf[8];
            #pragma unroll
            for (int kk = 0; kk < 8; ++kk)
                bf[kk] = *(const bf16x8*)&h2s[l16 * HP + kk * 32 + quad * 8];
            #pragma unroll
            for (int kk = 0; kk < 8; ++kk)
                acc = __builtin_amdgcn_mfma_f32_16x16x32_bf16(
                    w3f[kk], bf[kk], acc, 0, 0, 0);
            #pragma unroll
            for (int r = 0; r < 4; ++r)
                yreg[r] += dt * (acc[r] + b3r[r]);
            uint2 p; p.x = pk2(yreg[0], yreg[1]); p.y = pk2(yreg[2], yreg[3]);
            *(uint2*)&ybt[l16 * YPB + w * 16 + quad * 4] = p;
            float4 ov; ov.x = yreg[0]; ov.y = yreg[1]; ov.z = yreg[2]; ov.w = yreg[3];
            *(float4*)&out[(size_t)(b0 + l16) * (TSTEPS * DIM) + (size_t)t * DIM
                           + w * 16 + quad * 4] = ov;
        }
        __syncthreads();
    }
}

extern "C" void kernel_launch(void* const* d_in, const int* in_sizes, int n_in,
                              void* d_out, int out_size, void* d_ws, size_t ws_size,
                              hipStream_t stream) {
    const float* y0 = (const float*)d_in[0];
    const float* t  = (const float*)d_in[1];
    const float* W1 = (const float*)d_in[2];
    const float* b1 = (const float*)d_in[3];
    const float* W2 = (const float*)d_in[4];
    const float* b2 = (const float*)d_in[5];
    const float* W3 = (const float*)d_in[6];
    const float* b3 = (const float*)d_in[7];
    float* out = (float*)d_out;
    unsigned short* wf = (unsigned short*)d_ws;   // 12288 * 16B = 192 KiB

    prep_weights<<<48, 256, 0, stream>>>(W1, W2, W3, wf);
    ode_kernel<<<NBLOCKS, NTH, 0, stream>>>(y0, t, b1, b2, b3, wf, out);
}

// Round 3
// 385.076 us; speedup vs baseline: 1.2500x; 1.0266x over previous
//
#include <hip/hip_runtime.h>
#include <hip/hip_bf16.h>

#define BATCH   4096
#define DIM     64
#define HID     256
#define TSTEPS  200
#define SROWS   16                 // samples per block (MFMA N)
#define NBLOCKS (BATCH / SROWS)    // 256 blocks = 1 per CU
#define NTH     512                // 8 waves, 2 per SIMD

#define HP  264   // shorts: h1s/h2s row stride ([sample][h]) -> min-phase banks
#define YPB 72    // shorts: ybt row stride ([sample][d])

typedef __bf16 bf16_t;
typedef bf16_t bf16x8 __attribute__((ext_vector_type(8)));
typedef bf16_t bf16x2 __attribute__((ext_vector_type(2)));
typedef float  f32x4  __attribute__((ext_vector_type(4)));

__device__ __forceinline__ unsigned short f2bf(float f) {
    unsigned u = __builtin_bit_cast(unsigned, f);
    u += 0x7FFFu + ((u >> 16) & 1u);   // RNE
    return (unsigned short)(u >> 16);
}

#if __has_builtin(__builtin_amdgcn_cvt_pk_bf16_f32)
__device__ __forceinline__ unsigned pk2(float lo, float hi) {
    return __builtin_bit_cast(unsigned, __builtin_amdgcn_cvt_pk_bf16_f32(lo, hi));
}
#else
__device__ __forceinline__ unsigned pk2(float lo, float hi) {
    return (unsigned)f2bf(lo) | ((unsigned)f2bf(hi) << 16);
}
#endif

// ---------------------------------------------------------------------------
// Weight prep: fp32 row-major W[K][M] -> bf16 MFMA A-fragment order of W^T.
// A-frag element j: W^T[mt*16+l16][kk*32+quad*8+j] = W[kk*32+quad*8+j][mt*16+l16]
//   W1^T: u = (mt*2+kk)*64+lane            mt:0..15, kk:0..1
//   W2^T: u = 2048 + (mt*8+kk)*64+lane     mt:0..15, kk:0..7
//   W3^T: u = 10240 + (mt*8+kk)*64+lane    mt:0..3,  kk:0..7
// ---------------------------------------------------------------------------
__global__ void prep_weights(const float* __restrict__ W1,
                             const float* __restrict__ W2,
                             const float* __restrict__ W3,
                             unsigned short* __restrict__ ws) {
    int u = blockIdx.x * blockDim.x + threadIdx.x;
    if (u >= 12288) return;
    const int lane = u & 63, l16 = lane & 15, quad = lane >> 4;
    const float* src; int ld, m, k;
    if (u < 2048) {
        int r = u >> 6; int kk = r & 1; int mt = r >> 1;
        src = W1; ld = 256; m = mt * 16 + l16; k = kk * 32 + quad * 8;
    } else if (u < 10240) {
        int r = (u - 2048) >> 6; int kk = r & 7; int mt = r >> 3;
        src = W2; ld = 256; m = mt * 16 + l16; k = kk * 32 + quad * 8;
    } else {
        int r = (u - 10240) >> 6; int kk = r & 7; int mt = r >> 3;
        src = W3; ld = 64;  m = mt * 16 + l16; k = kk * 32 + quad * 8;
    }
    unsigned short tmp[8] __attribute__((aligned(16)));
    #pragma unroll
    for (int j = 0; j < 8; ++j)
        tmp[j] = f2bf(src[(size_t)(k + j) * ld + m]);
    *(uint4*)(ws + (size_t)u * 8) = *(const uint4*)tmp;
}

// ---------------------------------------------------------------------------
// Persistent ODE kernel, transposed: h^T[H x 16 samples].
// A = weight^T frags (registers), B = activations^T (LDS),
// C/D: row = h-idx (quad*4+r), col = sample (l16). Biases pre-loaded into
// the MFMA C operand (acc starts at bias, not zero).
// ---------------------------------------------------------------------------
__global__ void __launch_bounds__(NTH, 2)
ode_kernel(const float* __restrict__ y0,
           const float* __restrict__ tarr,
           const float* __restrict__ b1,
           const float* __restrict__ b2,
           const float* __restrict__ b3,
           const unsigned short* __restrict__ wf,
           float* __restrict__ out) {
    __shared__ __align__(16) unsigned short ybt[SROWS * YPB];
    __shared__ __align__(16) unsigned short h1s[SROWS * HP];
    __shared__ __align__(16) unsigned short h2s[SROWS * HP];

    const int tid  = threadIdx.x;
    const int w    = tid >> 6;        // wave 0..7
    const int lane = tid & 63;
    const int l16  = lane & 15;       // sample within tile
    const int quad = lane >> 4;
    const int b0   = blockIdx.x * SROWS;

    const float dt = tarr[1] - tarr[0];

    // --- resident weight fragments ---
    const bf16x8* wv = (const bf16x8*)wf;
    bf16x8 w1f[2][2], w2f[2][8], w3f[8];
    #pragma unroll
    for (int mt = 0; mt < 2; ++mt) {
        const int g = w * 2 + mt;
        #pragma unroll
        for (int kk = 0; kk < 2; ++kk) w1f[mt][kk] = wv[(g * 2 + kk) * 64 + lane];
        #pragma unroll
        for (int kk = 0; kk < 8; ++kk) w2f[mt][kk] = wv[2048 + (g * 8 + kk) * 64 + lane];
    }
    if (w < 4)
        #pragma unroll
        for (int kk = 0; kk < 8; ++kk) w3f[kk] = wv[10240 + (w * 8 + kk) * 64 + lane];

    // --- biases in MFMA C/D layout (row = base + quad*4 + r) ---
    f32x4 binit1[2], binit2[2], binit3;
    #pragma unroll
    for (int mt = 0; mt < 2; ++mt)
        #pragma unroll
        for (int r = 0; r < 4; ++r) {
            binit1[mt][r] = b1[w * 32 + mt * 16 + quad * 4 + r];
            binit2[mt][r] = b2[w * 32 + mt * 16 + quad * 4 + r];
        }

    // --- init y-state (waves 0-3) + t=0 output + ybt ---
    float yreg[4];
    float* outp = out;   // running per-thread output pointer (waves 0-3)
    if (w < 4) {
        #pragma unroll
        for (int r = 0; r < 4; ++r) binit3[r] = b3[w * 16 + quad * 4 + r];
        outp = out + (size_t)(b0 + l16) * (TSTEPS * DIM) + w * 16 + quad * 4;
        float4 v = *(const float4*)&y0[(size_t)(b0 + l16) * DIM + w * 16 + quad * 4];
        yreg[0] = v.x; yreg[1] = v.y; yreg[2] = v.z; yreg[3] = v.w;
        uint2 p; p.x = pk2(v.x, v.y); p.y = pk2(v.z, v.w);
        *(uint2*)&ybt[l16 * YPB + w * 16 + quad * 4] = p;
        *(float4*)outp = v;
        outp += DIM;
    }
    __syncthreads();

    const unsigned short* ybase  = &ybt[l16 * YPB];
    const unsigned short* h1base = &h1s[l16 * HP];
    const unsigned short* h2base = &h2s[l16 * HP];
    const int ep_off = l16 * HP + w * 32 + quad * 4;   // epilogue write offset

    for (int t = 1; t < TSTEPS; ++t) {
        // ---- GEMM1: h1^T = relu(W1^T @ y^T + b1) ----
        {
            f32x4 acc[2] = {binit1[0], binit1[1]};
            bf16x8 bfr[2];
            #pragma unroll
            for (int kk = 0; kk < 2; ++kk)
                bfr[kk] = *(const bf16x8*)&ybase[kk * 32 + quad * 8];
            #pragma unroll
            for (int kk = 0; kk < 2; ++kk)
                #pragma unroll
                for (int mt = 0; mt < 2; ++mt)
                    acc[mt] = __builtin_amdgcn_mfma_f32_16x16x32_bf16(
                        w1f[mt][kk], bfr[kk], acc[mt], 0, 0, 0);
            #pragma unroll
            for (int mt = 0; mt < 2; ++mt) {
                float v0 = acc[mt][0] > 0.f ? acc[mt][0] : 0.f;
                float v1 = acc[mt][1] > 0.f ? acc[mt][1] : 0.f;
                float v2 = acc[mt][2] > 0.f ? acc[mt][2] : 0.f;
                float v3 = acc[mt][3] > 0.f ? acc[mt][3] : 0.f;
                uint2 p; p.x = pk2(v0, v1); p.y = pk2(v2, v3);
                *(uint2*)&h1s[ep_off + mt * 16] = p;
            }
        }
        __syncthreads();

        // ---- GEMM2: h2^T = relu(W2^T @ h1^T + b2) ----
        {
            f32x4 acc[2] = {binit2[0], binit2[1]};
            bf16x8 bfr[8];
            #pragma unroll
            for (int kk = 0; kk < 8; ++kk)
                bfr[kk] = *(const bf16x8*)&h1base[kk * 32 + quad * 8];
            #pragma unroll
            for (int kk = 0; kk < 8; ++kk)
                #pragma unroll
                for (int mt = 0; mt < 2; ++mt)
                    acc[mt] = __builtin_amdgcn_mfma_f32_16x16x32_bf16(
                        w2f[mt][kk], bfr[kk], acc[mt], 0, 0, 0);
            #pragma unroll
            for (int mt = 0; mt < 2; ++mt) {
                float v0 = acc[mt][0] > 0.f ? acc[mt][0] : 0.f;
                float v1 = acc[mt][1] > 0.f ? acc[mt][1] : 0.f;
                float v2 = acc[mt][2] > 0.f ? acc[mt][2] : 0.f;
                float v3 = acc[mt][3] > 0.f ? acc[mt][3] : 0.f;
                uint2 p; p.x = pk2(v0, v1); p.y = pk2(v2, v3);
                *(uint2*)&h2s[ep_off + mt * 16] = p;
            }
        }
        __syncthreads();

        // ---- GEMM3 (waves 0-3): dy^T = W3^T @ h2^T + b3; y += dt*dy ----
        if (w < 4) {
            f32x4 acc = binit3;
            bf16x8 bfr[8];
            #pragma unroll
            for (int kk = 0; kk < 8; ++kk)
                bfr[kk] = *(const bf16x8*)&h2base[kk * 32 + quad * 8];
            #pragma unroll
            for (int kk = 0; kk < 8; ++kk)
                acc = __builtin_amdgcn_mfma_f32_16x16x32_bf16(
                    w3f[kk], bfr[kk], acc, 0, 0, 0);
            #pragma unroll
            for (int r = 0; r < 4; ++r)
                yreg[r] = __builtin_fmaf(dt, acc[r], yreg[r]);
            uint2 p; p.x = pk2(yreg[0], yreg[1]); p.y = pk2(yreg[2], yreg[3]);
            *(uint2*)&ybt[l16 * YPB + w * 16 + quad * 4] = p;
            float4 ov; ov.x = yreg[0]; ov.y = yreg[1]; ov.z = yreg[2]; ov.w = yreg[3];
            *(float4*)outp = ov;
            outp += DIM;
        }
        __syncthreads();
    }
}

extern "C" void kernel_launch(void* const* d_in, const int* in_sizes, int n_in,
                              void* d_out, int out_size, void* d_ws, size_t ws_size,
                              hipStream_t stream) {
    const float* y0 = (const float*)d_in[0];
    const float* t  = (const float*)d_in[1];
    const float* W1 = (const float*)d_in[2];
    const float* b1 = (const float*)d_in[3];
    const float* W2 = (const float*)d_in[4];
    const float* b2 = (const float*)d_in[5];
    const float* W3 = (const float*)d_in[6];
    const float* b3 = (const float*)d_in[7];
    float* out = (float*)d_out;
    unsigned short* wf = (unsigned short*)d_ws;   // 12288 * 16B = 192 KiB

    prep_weights<<<48, 256, 0, stream>>>(W1, W2, W3, wf);
    ode_kernel<<<NBLOCKS, NTH, 0, stream>>>(y0, t, b1, b2, b3, wf, out);
}